// Round 21
// baseline (375.436 us; speedup 1.0000x reference)
//
#include <hip/hip_runtime.h>
#include <math.h>

#define N 8192
#define D 256
#define BK 32
#define TILE 256
#define NB2 (N / TILE)                 // 32 panels of 256 rows
#define NBLK2 (NB2 * (NB2 + 1) / 2)    // 528 upper-triangular blocks (528%8==0)

typedef _Float16 half8 __attribute__((ext_vector_type(8)));
typedef float f32x4 __attribute__((ext_vector_type(4)));

constexpr float MARGIN = 0.5f;
constexpr float EPS_F  = 1e-10f;

// ---------------------------------------------------------------------------
// async global->LDS, 16B per lane. LDS dest = wave-uniform base + lane*16.
// ---------------------------------------------------------------------------
__device__ inline void load_lds16(const void* g, void* l) {
    __builtin_amdgcn_global_load_lds(
        (const __attribute__((address_space(1))) void*)g,
        (__attribute__((address_space(3))) void*)l, 16, 0, 0);
}

// ---------------------------------------------------------------------------
// Fused prologue (one dispatch, 512 blocks x 256 thr): r16-verified verbatim.
// ---------------------------------------------------------------------------
__global__ void prep_kernel(const float* __restrict__ xs,
                            const int* __restrict__ ys_raw,
                            _Float16* __restrict__ x16, float* __restrict__ sq,
                            int* __restrict__ lbl, int* __restrict__ hist16,
                            float* __restrict__ sums, float* __restrict__ out) {
    const int tid = threadIdx.x;
    const int rb  = blockIdx.x;

    {
        const int r   = tid >> 4;
        const int c16 = tid & 15;
        const int row = rb * 16 + r;

        const float4* src = (const float4*)xs + (size_t)row * (D / 4) + c16 * 4;
        const float4 v0 = src[0], v1 = src[1], v2 = src[2], v3 = src[3];

        half8 h0 = { (_Float16)v0.x, (_Float16)v0.y, (_Float16)v0.z, (_Float16)v0.w,
                     (_Float16)v1.x, (_Float16)v1.y, (_Float16)v1.z, (_Float16)v1.w };
        half8 h1 = { (_Float16)v2.x, (_Float16)v2.y, (_Float16)v2.z, (_Float16)v2.w,
                     (_Float16)v3.x, (_Float16)v3.y, (_Float16)v3.z, (_Float16)v3.w };

        _Float16* dst = x16 + (size_t)row * D + c16 * 16;
        *(half8*)dst       = h0;
        *(half8*)(dst + 8) = h1;

        float s = v0.x*v0.x + v0.y*v0.y + v0.z*v0.z + v0.w*v0.w
                + v1.x*v1.x + v1.y*v1.y + v1.z*v1.z + v1.w*v1.w
                + v2.x*v2.x + v2.y*v2.y + v2.z*v2.z + v2.w*v2.w
                + v3.x*v3.x + v3.y*v3.y + v3.z*v3.z + v3.w*v3.w;
#pragma unroll
        for (int off = 1; off < 16; off <<= 1) s += __shfl_xor(s, off);
        if (c16 == 0) sq[row] = s;
    }

    if (rb < 16) {
        __shared__ int bad_s;
        __shared__ int lh[64];
        const int base = rb * 512;
        if (tid == 0) bad_s = 0;
        if (tid < 64) lh[tid] = 0;
        __syncthreads();
        int bad = 0;
        for (int i = tid; i < 512; i += 256) bad |= (ys_raw[2 * (base + i) + 1] != 0);
        if (bad) atomicOr(&bad_s, 1);
        __syncthreads();
        const bool is64 = (bad_s == 0);
        for (int i = tid; i < 512; i += 256) {
            const int v = is64 ? ys_raw[2 * (base + i)] : ys_raw[base + i];
            lbl[base + i] = v;
            atomicAdd(&lh[v & 63], 1);
        }
        __syncthreads();
        if (tid < 64) hist16[rb * 64 + tid] = lh[tid];
    }

    if (rb >= 16 && rb < 48) {
        const int base = (rb - 16) * 4096;
#pragma unroll
        for (int k = 0; k < 16; ++k) sums[base + k * 256 + tid] = 0.f;
    }
    if (rb == 48 && tid == 0) out[0] = 0.f;
}

// ---------------------------------------------------------------------------
// 256x256-tile symmetric MFMA pair kernel, UNCAPPED registers (r14's spill
// root-cause removed: no launch_bounds -> 512-reg budget; arch+acc ~260 fits).
// 8 waves (2 wm x 4 wn), per-wave output 128x64 (acc 8x4). Single-barrier
// 3-buffer ring (r16-verified): vmcnt(4) -> barrier -> STAGE(t+2) -> reads ->
// MFMA. 4 gll/wave/stage (exact). setprio on MFMA, operand hoist last iter,
// per-XCD partial atomics. Epilogue = r14-verified 4-batch math.
// ---------------------------------------------------------------------------
__global__ void pair_kernel(
    const _Float16* __restrict__ x16, const int* __restrict__ lbl,
    const float* __restrict__ sq,
    float* __restrict__ sum_same8, float* __restrict__ sum_all8) {

    __shared__ _Float16 As[3][TILE * BK];   // 48 KB
    __shared__ _Float16 Bs[3][TILE * BK];   // 48 KB

    // ---- XCD-bijective swizzle (528 % 8 == 0 -> exact chunking) ----
    const int xcd = blockIdx.x & 7;
    const int t   = xcd * (NBLK2 / 8) + blockIdx.x / 8;
    float* __restrict__ sum_same = sum_same8 + (size_t)xcd * N;
    float* __restrict__ sum_all  = sum_all8  + (size_t)xcd * N;

    // ---- decode upper-triangular block index: t -> (bi, bj), bi<=bj ----
    int bj = (int)((sqrtf(8.f * (float)t + 1.f) - 1.f) * 0.5f);
    while ((bj + 1) * (bj + 2) / 2 <= t) ++bj;
    while (bj * (bj + 1) / 2 > t) --bj;
    const int bi    = t - bj * (bj + 1) / 2;
    const bool diag = (bi == bj);
    const int i0 = bi * TILE;
    const int j0 = bj * TILE;

    const int tid  = threadIdx.x;
    const int w    = tid >> 6;        // 0..7
    const int lane = tid & 63;
    const int wm   = w >> 2;          // 0..1 (row half: 128 rows)
    const int wn   = w & 3;           // 0..3 (col quarter: 64 cols)
    const int cl   = lane & 15;
    const int g    = lane >> 4;

    const int rowbase = i0 + wm * 128;
    const int colbase = j0 + wn * 64;

    f32x4 acc[8][4];
#pragma unroll
    for (int a = 0; a < 8; ++a)
#pragma unroll
        for (int b = 0; b < 4; ++b) acc[a][b] = (f32x4){0.f, 0.f, 0.f, 0.f};

    // staging: A tile 256x32 fp16 = 1024 16B-chunks, B same. Thread handles
    // chunks c0 and c0+512 of each; chunk c -> row=c>>2, kc=c&3 (linear LDS).
    // Every wave issues EXACTLY 4 global_load_lds per stage -> vmcnt exact.
    const int c0 = w * 64 + lane;     // 0..511
    const int r0 = c0 >> 2, kc0 = c0 & 3;
    const int r1 = r0 + 128;          // chunk c0+512

#define STAGE(buf, k0)                                                          \
    do {                                                                        \
        load_lds16(x16 + (size_t)(i0 + r0) * D + (k0) + kc0 * 8,                \
                   &As[buf][(size_t)(w * 64) * 8]);                             \
        load_lds16(x16 + (size_t)(j0 + r0) * D + (k0) + kc0 * 8,                \
                   &Bs[buf][(size_t)(w * 64) * 8]);                             \
        load_lds16(x16 + (size_t)(i0 + r1) * D + (k0) + kc0 * 8,                \
                   &As[buf][(size_t)(512 + w * 64) * 8]);                       \
        load_lds16(x16 + (size_t)(j0 + r1) * D + (k0) + kc0 * 8,                \
                   &Bs[buf][(size_t)(512 + w * 64) * 8]);                       \
    } while (0)

    STAGE(0, 0);           // prologue: stages 0 and 1 in flight (8 loads)
    STAGE(1, BK);

    float sqj_[4];
    int   yj_[4];

#pragma unroll
    for (int t8 = 0; t8 < 8; ++t8) {          // fully unrolled -> static %3
        const int cur = t8 % 3;

        // wait for tile t8 only: tile t8+1 (4 loads) stays in flight
        if (t8 < 7) asm volatile("s_waitcnt vmcnt(4)" ::: "memory");
        else        asm volatile("s_waitcnt vmcnt(0)" ::: "memory");
        __builtin_amdgcn_s_barrier();   // tile-t8 landed AND buf (t8-1)%3 free

        // stage tile t8+2 into buf (t8+2)%3 == (t8-1)%3 — safe after barrier
        if (t8 < 6) STAGE((t8 + 2) % 3, (t8 + 2) * BK);

        // last iter: issue epilogue operand loads; latency hides under MFMAs
        if (t8 == 7) {
#pragma unroll
            for (int nf = 0; nf < 4; ++nf) {
                const int c = colbase + nf * 16 + cl;
                sqj_[nf] = sq[c];
                yj_[nf]  = lbl[c];
            }
        }

        half8 af[8], bf[4];
#pragma unroll
        for (int mf = 0; mf < 8; ++mf)
            af[mf] = *(const half8*)&As[cur][(wm * 128 + mf * 16 + cl) * BK + g * 8];
#pragma unroll
        for (int nf = 0; nf < 4; ++nf)
            bf[nf] = *(const half8*)&Bs[cur][(wn * 64 + nf * 16 + cl) * BK + g * 8];

        __builtin_amdgcn_s_setprio(1);
#pragma unroll
        for (int mf = 0; mf < 8; ++mf)
#pragma unroll
            for (int nf = 0; nf < 4; ++nf)
                acc[mf][nf] = __builtin_amdgcn_mfma_f32_16x16x32_f16(
                    af[mf], bf[nf], acc[mf][nf], 0, 0, 0);
        __builtin_amdgcn_s_setprio(0);
        // no trailing barrier: next iter's leading barrier provides the
        // consume-done guarantee for the ring buffer.
    }
#undef STAGE

    // ---- epilogue (r14-verified math, 4 batches of 8 rows) ----
    // C layout (m89): col = lane&15 (j-local), row = (lane>>4)*4 + reg (i-local)
    float cs_all[4], cs_same[4];      // col sums (over i) -> rows of panel bj
#pragma unroll
    for (int nf = 0; nf < 4; ++nf) { cs_all[nf] = 0.f; cs_same[nf] = 0.f; }

#pragma unroll
    for (int b = 0; b < 4; ++b) {
        float rs_all[8], rs_same[8];
#pragma unroll
        for (int e = 0; e < 8; ++e) { rs_all[e] = 0.f; rs_same[e] = 0.f; }

#pragma unroll
        for (int mh = 0; mh < 2; ++mh) {
            const int mf = 2 * b + mh;
#pragma unroll
            for (int r = 0; r < 4; ++r) {
                const int row   = rowbase + mf * 16 + g * 4 + r;
                const float sqi = sq[row];
                const int   yi  = lbl[row];
#pragma unroll
                for (int nf = 0; nf < 4; ++nf) {
                    float d2   = sqi + sqj_[nf] - 2.f * acc[mf][nf][r];
                    float dist = __builtin_amdgcn_sqrtf(fmaxf(d2, EPS_F));
                    if (diag) {
                        const int col = colbase + nf * 16 + cl;
                        if (row == col) dist = 1e-5f;   // exact diagonal sqrt(EPS)
                    }
                    const float dm = (yi == yj_[nf]) ? dist : 0.f;
                    cs_all[nf] += dist;
                    cs_same[nf] += dm;
                    rs_all[mh * 4 + r] += dist;
                    rs_same[mh * 4 + r] += dm;
                }
            }
        }

        // row direction (off-diag only): value-split 8 values over 16 lanes +
        // closing mask-1 stage; even-cl lanes own entry e = cl>>1.
        if (!diag) {
#define RSTEP(h, mask, bit)                                                     \
            {                                                                   \
                const bool hi = (cl >> (bit)) & 1;                              \
                _Pragma("unroll")                                               \
                for (int j = 0; j < (h); ++j) {                                 \
                    float sa_ = hi ? rs_all[j] : rs_all[j + (h)];               \
                    float ka_ = hi ? rs_all[j + (h)] : rs_all[j];               \
                    rs_all[j] = ka_ + __shfl_xor(sa_, (mask));                  \
                    float ss_ = hi ? rs_same[j] : rs_same[j + (h)];             \
                    float ks_ = hi ? rs_same[j + (h)] : rs_same[j];             \
                    rs_same[j] = ks_ + __shfl_xor(ss_, (mask));                 \
                }                                                               \
            }
            RSTEP(4, 8, 3)
            RSTEP(2, 4, 2)
            RSTEP(1, 2, 1)
#undef RSTEP
            rs_all[0]  += __shfl_xor(rs_all[0], 1);   // closing stage (mask 1)
            rs_same[0] += __shfl_xor(rs_same[0], 1);

            const int e    = cl >> 1;
            const int rrow = rowbase + (2 * b + (e >> 2)) * 16 + g * 4 + (e & 3);
            if (!(cl & 1)) {
                atomicAdd(&sum_all[rrow],  rs_all[0]);
                atomicAdd(&sum_same[rrow], rs_same[0]);
            }
        }
    }

    // ---- col direction: value-split reduce 4 values over 4 g-lanes
    {
        const bool hi1 = (g >> 1) & 1;
#pragma unroll
        for (int j = 0; j < 2; ++j) {
            float sa_ = hi1 ? cs_all[j] : cs_all[j + 2];
            float ka_ = hi1 ? cs_all[j + 2] : cs_all[j];
            cs_all[j] = ka_ + __shfl_xor(sa_, 32);
            float ss_ = hi1 ? cs_same[j] : cs_same[j + 2];
            float ks_ = hi1 ? cs_same[j + 2] : cs_same[j];
            cs_same[j] = ks_ + __shfl_xor(ss_, 32);
        }
        const bool hi0 = g & 1;
        {
            float sa_ = hi0 ? cs_all[0] : cs_all[1];
            float ka_ = hi0 ? cs_all[1] : cs_all[0];
            cs_all[0] = ka_ + __shfl_xor(sa_, 16);
            float ss_ = hi0 ? cs_same[0] : cs_same[1];
            float ks_ = hi0 ? cs_same[1] : cs_same[0];
            cs_same[0] = ks_ + __shfl_xor(ss_, 16);
        }
        const int ccol = colbase + g * 16 + cl;
        atomicAdd(&sum_all[ccol],  cs_all[0]);
        atomicAdd(&sum_same[ccol], cs_same[0]);
    }
}

// ---------------------------------------------------------------------------
// Finalize: 32 blocks x 256 thr, one row per thread (r16-verified verbatim).
// ---------------------------------------------------------------------------
__global__ void finalize_kernel(const float* __restrict__ sum_same8,
                                const float* __restrict__ sum_all8,
                                const int* __restrict__ lbl,
                                const int* __restrict__ hist16,
                                float* __restrict__ out) {
    __shared__ int lh[64];
    __shared__ float wsums[4];
    const int tid = threadIdx.x;
    if (tid < 64) {
        int h = 0;
#pragma unroll
        for (int b = 0; b < 16; ++b) h += hist16[b * 64 + tid];
        lh[tid] = h;
    }
    __syncthreads();

    const int row = blockIdx.x * 256 + tid;
    float ss = 0.f, sa = 0.f;
#pragma unroll
    for (int x = 0; x < 8; ++x) {
        ss += sum_same8[(size_t)x * N + row];
        sa += sum_all8[(size_t)x * N + row];
    }

    const float cnt = (float)lh[lbl[row]];
    const float ap  = ss / cnt;
    const float an  = (sa - ss) / ((float)N - cnt);
    float local = fmaxf(ap - an + MARGIN, 0.f);

#pragma unroll
    for (int off = 32; off > 0; off >>= 1) local += __shfl_down(local, off);
    const int lane = tid & 63, wave = tid >> 6;
    if (lane == 0) wsums[wave] = local;
    __syncthreads();
    if (tid == 0)
        atomicAdd(out, (wsums[0] + wsums[1] + wsums[2] + wsums[3]) / (float)N);
}

// ---------------------------------------------------------------------------
extern "C" void kernel_launch(void* const* d_in, const int* in_sizes, int n_in,
                              void* d_out, int out_size, void* d_ws, size_t ws_size,
                              hipStream_t stream) {
    const float* xs     = (const float*)d_in[0];
    const int*   ys_raw = (const int*)d_in[1];

    float* ws        = (float*)d_ws;
    float* sum_same8 = ws;                         // [8][N]
    float* sum_all8  = ws + 8 * N;                 // [8][N]
    float* sqv       = ws + 16 * N;                // [N]
    int*   lbl       = (int*)(ws + 17 * N);        // [N]
    int*   hist16    = (int*)(ws + 18 * N);        // [16*64]
    _Float16* x16    = (_Float16*)(ws + 18 * N + 1024);  // [N*D] fp16 (4 MB)

    prep_kernel<<<N / 16, 256, 0, stream>>>(xs, ys_raw, x16, sqv, lbl, hist16,
                                            sum_same8, (float*)d_out);

    pair_kernel<<<NBLK2, 512, 0, stream>>>(x16, lbl, sqv, sum_same8, sum_all8);

    finalize_kernel<<<32, 256, 0, stream>>>(sum_same8, sum_all8, lbl, hist16,
                                            (float*)d_out);
}

// Round 22
// 50.871 us; speedup vs baseline: 7.3802x; 7.3802x over previous
//
#include <hip/hip_runtime.h>
#include <math.h>

#define N 8192
#define D 256
#define BK 32
#define TILE 128
#define NB (N / TILE)              // 64 panels
#define NBLK (NB * (NB + 1) / 2)   // 2080 upper-triangular blocks

typedef _Float16 half8 __attribute__((ext_vector_type(8)));
typedef float f32x4 __attribute__((ext_vector_type(4)));

constexpr float MARGIN = 0.5f;
constexpr float EPS_F  = 1e-10f;

// ---------------------------------------------------------------------------
// async global->LDS, 16B per lane. LDS dest = wave-uniform base + lane*16.
// ---------------------------------------------------------------------------
__device__ inline void load_lds16(const void* g, void* l) {
    __builtin_amdgcn_global_load_lds(
        (const __attribute__((address_space(1))) void*)g,
        (__attribute__((address_space(3))) void*)l, 16, 0, 0);
}

// ---------------------------------------------------------------------------
// Fused prologue (one dispatch, 512 blocks x 256 thr):
//   all blocks  : fp32 -> fp16 row-major convert + exact fp32 row sq-norms
//   blocks 0-15 : label detect/normalize + per-block 64-bin histogram slice
//   blocks 16-47: zero the 8 per-XCD partial sum arrays (16N floats)
//   block 48    : zero out[0]
// ---------------------------------------------------------------------------
__global__ void prep_kernel(const float* __restrict__ xs,
                            const int* __restrict__ ys_raw,
                            _Float16* __restrict__ x16, float* __restrict__ sq,
                            int* __restrict__ lbl, int* __restrict__ hist16,
                            float* __restrict__ sums, float* __restrict__ out) {
    const int tid = threadIdx.x;
    const int rb  = blockIdx.x;

    // ---- convert + sq (every block handles a 16-row tile) ----
    {
        const int r   = tid >> 4;
        const int c16 = tid & 15;
        const int row = rb * 16 + r;

        const float4* src = (const float4*)xs + (size_t)row * (D / 4) + c16 * 4;
        const float4 v0 = src[0], v1 = src[1], v2 = src[2], v3 = src[3];

        half8 h0 = { (_Float16)v0.x, (_Float16)v0.y, (_Float16)v0.z, (_Float16)v0.w,
                     (_Float16)v1.x, (_Float16)v1.y, (_Float16)v1.z, (_Float16)v1.w };
        half8 h1 = { (_Float16)v2.x, (_Float16)v2.y, (_Float16)v2.z, (_Float16)v2.w,
                     (_Float16)v3.x, (_Float16)v3.y, (_Float16)v3.z, (_Float16)v3.w };

        _Float16* dst = x16 + (size_t)row * D + c16 * 16;
        *(half8*)dst       = h0;
        *(half8*)(dst + 8) = h1;

        float s = v0.x*v0.x + v0.y*v0.y + v0.z*v0.z + v0.w*v0.w
                + v1.x*v1.x + v1.y*v1.y + v1.z*v1.z + v1.w*v1.w
                + v2.x*v2.x + v2.y*v2.y + v2.z*v2.z + v2.w*v2.w
                + v3.x*v3.x + v3.y*v3.y + v3.z*v3.z + v3.w*v3.w;
#pragma unroll
        for (int off = 1; off < 16; off <<= 1) s += __shfl_xor(s, off);
        if (c16 == 0) sq[row] = s;
    }

    // ---- labels + histogram slice (blocks 0-15, 512 labels each) ----
    if (rb < 16) {
        __shared__ int bad_s;
        __shared__ int lh[64];
        const int base = rb * 512;
        if (tid == 0) bad_s = 0;
        if (tid < 64) lh[tid] = 0;
        __syncthreads();
        int bad = 0;
        for (int i = tid; i < 512; i += 256) bad |= (ys_raw[2 * (base + i) + 1] != 0);
        if (bad) atomicOr(&bad_s, 1);
        __syncthreads();
        const bool is64 = (bad_s == 0);
        for (int i = tid; i < 512; i += 256) {
            const int v = is64 ? ys_raw[2 * (base + i)] : ys_raw[base + i];
            lbl[base + i] = v;
            atomicAdd(&lh[v & 63], 1);
        }
        __syncthreads();
        if (tid < 64) hist16[rb * 64 + tid] = lh[tid];   // exclusive slice
    }

    // ---- zero per-XCD partials (blocks 16-47: 32 blocks x 4096 floats = 16N) ----
    if (rb >= 16 && rb < 48) {
        const int base = (rb - 16) * 4096;
#pragma unroll
        for (int k = 0; k < 16; ++k) sums[base + k * 256 + tid] = 0.f;
    }
    if (rb == 48 && tid == 0) out[0] = 0.f;
}

// ---------------------------------------------------------------------------
// Symmetric MFMA pair kernel (r16-verified optimum), SINGLE-barrier 3-buffer
// ring: per k-iter: vmcnt(4) -> barrier -> STAGE(t+2) -> ds_read -> MFMA.
// Safety: stage of tile t+2 writes buf (t+2)%3 == (t-1)%3, whose readers all
// completed before barrier(t). Steady vmcnt(4) is per-wave exact (4 gll/wave
// per stage; outstanding = tiles {t, t+1} = 8 at the wait -> drains tile t).
// 128x128 tile, 4 waves (2x2 of 64x64), setprio on MFMA, per-XCD atomics.
// ---------------------------------------------------------------------------
__global__ __launch_bounds__(256, 3) void pair_kernel(
    const _Float16* __restrict__ x16, const int* __restrict__ lbl,
    const float* __restrict__ sq,
    float* __restrict__ sum_same8, float* __restrict__ sum_all8) {

    __shared__ _Float16 As[3][TILE * BK];   // 24 KB
    __shared__ _Float16 Bs[3][TILE * BK];   // 24 KB

    // ---- XCD-bijective swizzle (2080 % 8 == 0 -> exact chunking) ----
    const int xcd = blockIdx.x & 7;         // == XCD under round-robin dispatch
    const int t   = xcd * (NBLK / 8) + blockIdx.x / 8;
    float* __restrict__ sum_same = sum_same8 + (size_t)xcd * N;
    float* __restrict__ sum_all  = sum_all8  + (size_t)xcd * N;

    // ---- decode upper-triangular block index: t -> (bi, bj), bi<=bj ----
    int bj = (int)((sqrtf(8.f * (float)t + 1.f) - 1.f) * 0.5f);
    while ((bj + 1) * (bj + 2) / 2 <= t) ++bj;
    while (bj * (bj + 1) / 2 > t) --bj;
    const int bi    = t - bj * (bj + 1) / 2;
    const bool diag = (bi == bj);
    const int i0 = bi * TILE;
    const int j0 = bj * TILE;

    const int tid  = threadIdx.x;
    const int w    = tid >> 6;
    const int lane = tid & 63;
    const int wm   = w >> 1;
    const int wn   = w & 1;
    const int cl   = lane & 15;
    const int g    = lane >> 4;

    f32x4 acc[4][4];
#pragma unroll
    for (int a = 0; a < 4; ++a)
#pragma unroll
        for (int b = 0; b < 4; ++b) acc[a][b] = (f32x4){0.f, 0.f, 0.f, 0.f};

    // staging: 512 16B-chunks per tile; chunk c -> row=c>>2, kc=c&3 (linear LDS)
    const int c0 = w * 64 + lane;
    const int r0 = c0 >> 2, kc0 = c0 & 3;
    const int c1 = 256 + c0;
    const int r1 = c1 >> 2, kc1 = c1 & 3;

    // every wave issues EXACTLY 4 global_load_lds per stage -> per-wave vmcnt
    // accounting is uniform and exact.
#define STAGE(buf, k0)                                                          \
    do {                                                                        \
        load_lds16(x16 + (size_t)(i0 + r0) * D + (k0) + kc0 * 8,                \
                   &As[buf][(size_t)(w * 64) * 8]);                             \
        load_lds16(x16 + (size_t)(j0 + r0) * D + (k0) + kc0 * 8,                \
                   &Bs[buf][(size_t)(w * 64) * 8]);                             \
        load_lds16(x16 + (size_t)(i0 + r1) * D + (k0) + kc1 * 8,                \
                   &As[buf][(size_t)(256 + w * 64) * 8]);                       \
        load_lds16(x16 + (size_t)(j0 + r1) * D + (k0) + kc1 * 8,                \
                   &Bs[buf][(size_t)(256 + w * 64) * 8]);                       \
    } while (0)

    STAGE(0, 0);           // prologue: stages 0 and 1 in flight (8 loads)
    STAGE(1, BK);

    const int colbase = j0 + wn * 64;
    float sqj_[4];
    int   yj_[4];

#pragma unroll
    for (int t8 = 0; t8 < 8; ++t8) {          // fully unrolled -> static %3
        const int cur = t8 % 3;

        // wait for tile t8 only: tile t8+1 (4 loads) stays in flight
        if (t8 < 7) asm volatile("s_waitcnt vmcnt(4)" ::: "memory");
        else        asm volatile("s_waitcnt vmcnt(0)" ::: "memory");
        __builtin_amdgcn_s_barrier();   // all waves' tile-t8 loads landed AND
                                        // all waves done reading buf (t8-1)%3

        // stage tile t8+2 into buf (t8+2)%3 == (t8-1)%3 — safe after barrier
        if (t8 < 6) STAGE((t8 + 2) % 3, (t8 + 2) * BK);

        // last iter: issue epilogue operand loads; latency hides under MFMAs
        if (t8 == 7) {
#pragma unroll
            for (int nf = 0; nf < 4; ++nf) {
                const int c = colbase + nf * 16 + cl;
                sqj_[nf] = sq[c];
                yj_[nf]  = lbl[c];
            }
        }

        half8 af[4], bf[4];
#pragma unroll
        for (int mf = 0; mf < 4; ++mf)
            af[mf] = *(const half8*)&As[cur][(wm * 64 + mf * 16 + cl) * BK + g * 8];
#pragma unroll
        for (int nf = 0; nf < 4; ++nf)
            bf[nf] = *(const half8*)&Bs[cur][(wn * 64 + nf * 16 + cl) * BK + g * 8];

        __builtin_amdgcn_s_setprio(1);
#pragma unroll
        for (int mf = 0; mf < 4; ++mf)
#pragma unroll
            for (int nf = 0; nf < 4; ++nf)
                acc[mf][nf] = __builtin_amdgcn_mfma_f32_16x16x32_f16(
                    af[mf], bf[nf], acc[mf][nf], 0, 0, 0);
        __builtin_amdgcn_s_setprio(0);
        // no trailing barrier: next iter's leading barrier provides the
        // consume-done guarantee for the ring buffer.
    }
#undef STAGE

    // ---- epilogue (r7/r10-verified) ----
    // C layout (m89): col = lane&15 (j-local), row = (lane>>4)*4 + reg (i-local)
    const int rowbase = i0 + wm * 64;

    float cs_all[4], cs_same[4];      // col sums (over i) -> rows of panel bj
#pragma unroll
    for (int nf = 0; nf < 4; ++nf) { cs_all[nf] = 0.f; cs_same[nf] = 0.f; }

    // two batches of 8 rows each (mf in {2b, 2b+1}) to limit register peak
#pragma unroll
    for (int b = 0; b < 2; ++b) {
        float rs_all[8], rs_same[8];
#pragma unroll
        for (int e = 0; e < 8; ++e) { rs_all[e] = 0.f; rs_same[e] = 0.f; }

#pragma unroll
        for (int mh = 0; mh < 2; ++mh) {
            const int mf = 2 * b + mh;
#pragma unroll
            for (int r = 0; r < 4; ++r) {
                const int row   = rowbase + mf * 16 + g * 4 + r;
                const float sqi = sq[row];
                const int   yi  = lbl[row];
#pragma unroll
                for (int nf = 0; nf < 4; ++nf) {
                    float d2   = sqi + sqj_[nf] - 2.f * acc[mf][nf][r];
                    float dist = __builtin_amdgcn_sqrtf(fmaxf(d2, EPS_F));
                    if (diag) {
                        const int col = colbase + nf * 16 + cl;
                        if (row == col) dist = 1e-5f;   // exact diagonal sqrt(EPS)
                    }
                    const float dm = (yi == yj_[nf]) ? dist : 0.f;
                    cs_all[nf] += dist;
                    cs_same[nf] += dm;
                    rs_all[mh * 4 + r] += dist;
                    rs_same[mh * 4 + r] += dm;
                }
            }
        }

        // row direction (off-diag only): value-split 8 values over 16 lanes,
        // closing mask-1 stage completes the 16-lane sum; even-cl lanes own
        // entry e = cl>>1.
        if (!diag) {
#define RSTEP(h, mask, bit)                                                     \
            {                                                                   \
                const bool hi = (cl >> (bit)) & 1;                              \
                _Pragma("unroll")                                               \
                for (int j = 0; j < (h); ++j) {                                 \
                    float sa_ = hi ? rs_all[j] : rs_all[j + (h)];               \
                    float ka_ = hi ? rs_all[j + (h)] : rs_all[j];               \
                    rs_all[j] = ka_ + __shfl_xor(sa_, (mask));                  \
                    float ss_ = hi ? rs_same[j] : rs_same[j + (h)];             \
                    float ks_ = hi ? rs_same[j + (h)] : rs_same[j];             \
                    rs_same[j] = ks_ + __shfl_xor(ss_, (mask));                 \
                }                                                               \
            }
            RSTEP(4, 8, 3)
            RSTEP(2, 4, 2)
            RSTEP(1, 2, 1)
#undef RSTEP
            rs_all[0]  += __shfl_xor(rs_all[0], 1);   // closing stage (mask 1)
            rs_same[0] += __shfl_xor(rs_same[0], 1);

            const int e    = cl >> 1;
            const int rrow = rowbase + (2 * b + (e >> 2)) * 16 + g * 4 + (e & 3);
            if (!(cl & 1)) {
                atomicAdd(&sum_all[rrow],  rs_all[0]);
                atomicAdd(&sum_same[rrow], rs_same[0]);
            }
        }
    }

    // ---- col direction: value-split reduce 4 values over 4 g-lanes
    {
        const bool hi1 = (g >> 1) & 1;
#pragma unroll
        for (int j = 0; j < 2; ++j) {
            float sa_ = hi1 ? cs_all[j] : cs_all[j + 2];
            float ka_ = hi1 ? cs_all[j + 2] : cs_all[j];
            cs_all[j] = ka_ + __shfl_xor(sa_, 32);
            float ss_ = hi1 ? cs_same[j] : cs_same[j + 2];
            float ks_ = hi1 ? cs_same[j + 2] : cs_same[j];
            cs_same[j] = ks_ + __shfl_xor(ss_, 32);
        }
        const bool hi0 = g & 1;
        {
            float sa_ = hi0 ? cs_all[0] : cs_all[1];
            float ka_ = hi0 ? cs_all[1] : cs_all[0];
            cs_all[0] = ka_ + __shfl_xor(sa_, 16);
            float ss_ = hi0 ? cs_same[0] : cs_same[1];
            float ks_ = hi0 ? cs_same[1] : cs_same[0];
            cs_same[0] = ks_ + __shfl_xor(ss_, 16);
        }
        const int ccol = colbase + g * 16 + cl;
        atomicAdd(&sum_all[ccol],  cs_all[0]);
        atomicAdd(&sum_same[ccol], cs_same[0]);
    }
}

// ---------------------------------------------------------------------------
// Finalize: 32 blocks x 256 thr, one row per thread. Sums the 8 per-XCD
// partials; histogram from the 16 precomputed slices.
// ---------------------------------------------------------------------------
__global__ void finalize_kernel(const float* __restrict__ sum_same8,
                                const float* __restrict__ sum_all8,
                                const int* __restrict__ lbl,
                                const int* __restrict__ hist16,
                                float* __restrict__ out) {
    __shared__ int lh[64];
    __shared__ float wsums[4];
    const int tid = threadIdx.x;
    if (tid < 64) {
        int h = 0;
#pragma unroll
        for (int b = 0; b < 16; ++b) h += hist16[b * 64 + tid];
        lh[tid] = h;
    }
    __syncthreads();

    const int row = blockIdx.x * 256 + tid;
    float ss = 0.f, sa = 0.f;
#pragma unroll
    for (int x = 0; x < 8; ++x) {
        ss += sum_same8[(size_t)x * N + row];
        sa += sum_all8[(size_t)x * N + row];
    }

    const float cnt = (float)lh[lbl[row]];
    const float ap  = ss / cnt;
    const float an  = (sa - ss) / ((float)N - cnt);
    float local = fmaxf(ap - an + MARGIN, 0.f);

#pragma unroll
    for (int off = 32; off > 0; off >>= 1) local += __shfl_down(local, off);
    const int lane = tid & 63, wave = tid >> 6;
    if (lane == 0) wsums[wave] = local;
    __syncthreads();
    if (tid == 0)
        atomicAdd(out, (wsums[0] + wsums[1] + wsums[2] + wsums[3]) / (float)N);
}

// ---------------------------------------------------------------------------
extern "C" void kernel_launch(void* const* d_in, const int* in_sizes, int n_in,
                              void* d_out, int out_size, void* d_ws, size_t ws_size,
                              hipStream_t stream) {
    const float* xs     = (const float*)d_in[0];
    const int*   ys_raw = (const int*)d_in[1];

    float* ws        = (float*)d_ws;
    float* sum_same8 = ws;                         // [8][N]
    float* sum_all8  = ws + 8 * N;                 // [8][N]
    float* sqv       = ws + 16 * N;                // [N]
    int*   lbl       = (int*)(ws + 17 * N);        // [N]
    int*   hist16    = (int*)(ws + 18 * N);        // [16*64]
    _Float16* x16    = (_Float16*)(ws + 18 * N + 1024);  // [N*D] fp16 (4 MB)

    prep_kernel<<<N / 16, 256, 0, stream>>>(xs, ys_raw, x16, sqv, lbl, hist16,
                                            sum_same8, (float*)d_out);

    pair_kernel<<<NBLK, 256, 0, stream>>>(x16, lbl, sqv, sum_same8, sum_all8);

    finalize_kernel<<<32, 256, 0, stream>>>(sum_same8, sum_all8, lbl, hist16,
                                            (float*)d_out);
}

// Round 23
// 50.268 us; speedup vs baseline: 7.4687x; 1.0120x over previous
//
#include <hip/hip_runtime.h>
#include <hip/hip_fp8.h>
#include <math.h>

#define N 8192
#define D 256
#define BK 32                      // k-elements (= bytes in fp8) per tile step
#define TILE 128
#define NB (N / TILE)              // 64 panels
#define NBLK (NB * (NB + 1) / 2)   // 2080 upper-triangular blocks

typedef float f32x4 __attribute__((ext_vector_type(4)));

constexpr float MARGIN = 0.5f;
constexpr float EPS_F  = 1e-10f;

// ---------------------------------------------------------------------------
// async global->LDS, 16B per lane. LDS dest = wave-uniform base + lane*16.
// ---------------------------------------------------------------------------
__device__ inline void load_lds16(const void* g, void* l) {
    __builtin_amdgcn_global_load_lds(
        (const __attribute__((address_space(1))) void*)g,
        (__attribute__((address_space(3))) void*)l, 16, 0, 0);
}

// pack 4 floats into 4 OCP e4m3 bytes
__device__ inline unsigned int pk4(float a, float b, float c, float d) {
    return (unsigned int)__hip_fp8_e4m3(a).__x
         | ((unsigned int)__hip_fp8_e4m3(b).__x << 8)
         | ((unsigned int)__hip_fp8_e4m3(c).__x << 16)
         | ((unsigned int)__hip_fp8_e4m3(d).__x << 24);
}

// ---------------------------------------------------------------------------
// Fused prologue (one dispatch, 512 blocks x 256 thr):
//   all blocks  : fp32 -> fp8 e4m3 row-major convert + exact fp32 row sq-norms
//   blocks 0-15 : label detect/normalize + per-block 64-bin histogram slice
//   blocks 16-47: zero the 8 per-XCD partial sum arrays (16N floats)
//   block 48    : zero out[0]
// ---------------------------------------------------------------------------
__global__ void prep_kernel(const float* __restrict__ xs,
                            const int* __restrict__ ys_raw,
                            unsigned char* __restrict__ x8, float* __restrict__ sq,
                            int* __restrict__ lbl, int* __restrict__ hist16,
                            float* __restrict__ sums, float* __restrict__ out) {
    const int tid = threadIdx.x;
    const int rb  = blockIdx.x;

    // ---- convert + sq (every block handles a 16-row tile) ----
    {
        const int r   = tid >> 4;
        const int c16 = tid & 15;
        const int row = rb * 16 + r;

        const float4* src = (const float4*)xs + (size_t)row * (D / 4) + c16 * 4;
        const float4 v0 = src[0], v1 = src[1], v2 = src[2], v3 = src[3];

        uint4 pk;
        pk.x = pk4(v0.x, v0.y, v0.z, v0.w);
        pk.y = pk4(v1.x, v1.y, v1.z, v1.w);
        pk.z = pk4(v2.x, v2.y, v2.z, v2.w);
        pk.w = pk4(v3.x, v3.y, v3.z, v3.w);
        *(uint4*)(x8 + (size_t)row * D + c16 * 16) = pk;

        float s = v0.x*v0.x + v0.y*v0.y + v0.z*v0.z + v0.w*v0.w
                + v1.x*v1.x + v1.y*v1.y + v1.z*v1.z + v1.w*v1.w
                + v2.x*v2.x + v2.y*v2.y + v2.z*v2.z + v2.w*v2.w
                + v3.x*v3.x + v3.y*v3.y + v3.z*v3.z + v3.w*v3.w;
#pragma unroll
        for (int off = 1; off < 16; off <<= 1) s += __shfl_xor(s, off);
        if (c16 == 0) sq[row] = s;
    }

    // ---- labels + histogram slice (blocks 0-15, 512 labels each) ----
    if (rb < 16) {
        __shared__ int bad_s;
        __shared__ int lh[64];
        const int base = rb * 512;
        if (tid == 0) bad_s = 0;
        if (tid < 64) lh[tid] = 0;
        __syncthreads();
        int bad = 0;
        for (int i = tid; i < 512; i += 256) bad |= (ys_raw[2 * (base + i) + 1] != 0);
        if (bad) atomicOr(&bad_s, 1);
        __syncthreads();
        const bool is64 = (bad_s == 0);
        for (int i = tid; i < 512; i += 256) {
            const int v = is64 ? ys_raw[2 * (base + i)] : ys_raw[base + i];
            lbl[base + i] = v;
            atomicAdd(&lh[v & 63], 1);
        }
        __syncthreads();
        if (tid < 64) hist16[rb * 64 + tid] = lh[tid];   // exclusive slice
    }

    // ---- zero per-XCD partials (blocks 16-47: 32 blocks x 4096 floats = 16N) ----
    if (rb >= 16 && rb < 48) {
        const int base = (rb - 16) * 4096;
#pragma unroll
        for (int k = 0; k < 16; ++k) sums[base + k * 256 + tid] = 0.f;
    }
    if (rb == 48 && tid == 0) out[0] = 0.f;
}

// ---------------------------------------------------------------------------
// Symmetric MFMA pair kernel — r16-verified single-barrier 3-buffer ring,
// ported to fp8 e4m3 (mfma_f32_16x16x32_fp8_fp8, same MFMA rate as f16,
// HALF the staging bytes): 2 gll/wave/stage, steady vmcnt(2), 4 KB tiles.
// LDS layout [kc][row][16] (k-major chunks; gll-linear): fragment ds_read_b64
// at (g>>1)*2048 + row*16 + (g&1)*8 -> 2 lanes/bank-pair = conflict-free.
// 128x128 tile, 4 waves (2x2 of 64x64), setprio on MFMA, per-XCD atomics.
// ---------------------------------------------------------------------------
__global__ __launch_bounds__(256, 3) void pair_kernel(
    const unsigned char* __restrict__ x8, const int* __restrict__ lbl,
    const float* __restrict__ sq,
    float* __restrict__ sum_same8, float* __restrict__ sum_all8) {

    __shared__ unsigned char As[3][TILE * BK];   // 12 KB
    __shared__ unsigned char Bs[3][TILE * BK];   // 12 KB

    // ---- XCD-bijective swizzle (2080 % 8 == 0 -> exact chunking) ----
    const int xcd = blockIdx.x & 7;         // == XCD under round-robin dispatch
    const int t   = xcd * (NBLK / 8) + blockIdx.x / 8;
    float* __restrict__ sum_same = sum_same8 + (size_t)xcd * N;
    float* __restrict__ sum_all  = sum_all8  + (size_t)xcd * N;

    // ---- decode upper-triangular block index: t -> (bi, bj), bi<=bj ----
    int bj = (int)((sqrtf(8.f * (float)t + 1.f) - 1.f) * 0.5f);
    while ((bj + 1) * (bj + 2) / 2 <= t) ++bj;
    while (bj * (bj + 1) / 2 > t) --bj;
    const int bi    = t - bj * (bj + 1) / 2;
    const bool diag = (bi == bj);
    const int i0 = bi * TILE;
    const int j0 = bj * TILE;

    const int tid  = threadIdx.x;
    const int w    = tid >> 6;
    const int lane = tid & 63;
    const int wm   = w >> 1;
    const int wn   = w & 1;
    const int cl   = lane & 15;
    const int g    = lane >> 4;

    f32x4 acc[4][4];
#pragma unroll
    for (int a = 0; a < 4; ++a)
#pragma unroll
        for (int b = 0; b < 4; ++b) acc[a][b] = (f32x4){0.f, 0.f, 0.f, 0.f};

    // staging: 256 16B-chunks per tile (128 rows x 32 B). chunk c = w*64+lane:
    // kc = c>>7 (which 16B k-chunk), row = c&127. LDS offset = c*16 (linear).
    // Every wave issues EXACTLY 2 global_load_lds per stage -> vmcnt exact.
    const int ch   = w * 64 + lane;
    const int crow = ch & 127;
    const int ckc  = ch >> 7;

#define STAGE(buf, k0)                                                          \
    do {                                                                        \
        load_lds16(x8 + (size_t)(i0 + crow) * D + (k0) + ckc * 16,              \
                   &As[buf][(size_t)(w * 64) * 16]);                            \
        load_lds16(x8 + (size_t)(j0 + crow) * D + (k0) + ckc * 16,              \
                   &Bs[buf][(size_t)(w * 64) * 16]);                            \
    } while (0)

    STAGE(0, 0);           // prologue: stages 0 and 1 in flight (4 loads)
    STAGE(1, BK);

    const int colbase = j0 + wn * 64;
    float sqj_[4];
    int   yj_[4];

    // fragment base within a buffer: k-group g -> chunk g>>1, byte (g&1)*8
    const int fragk = (g >> 1) * 2048 + (g & 1) * 8;

#pragma unroll
    for (int t8 = 0; t8 < 8; ++t8) {          // fully unrolled -> static %3
        const int cur = t8 % 3;

        // wait for tile t8 only: tile t8+1 (2 loads) stays in flight
        if (t8 < 7) asm volatile("s_waitcnt vmcnt(2)" ::: "memory");
        else        asm volatile("s_waitcnt vmcnt(0)" ::: "memory");
        __builtin_amdgcn_s_barrier();   // all waves' tile-t8 loads landed AND
                                        // all waves done reading buf (t8-1)%3

        // stage tile t8+2 into buf (t8+2)%3 == (t8-1)%3 — safe after barrier
        if (t8 < 6) STAGE((t8 + 2) % 3, (t8 + 2) * BK);

        // last iter: issue epilogue operand loads; latency hides under MFMAs
        if (t8 == 7) {
#pragma unroll
            for (int nf = 0; nf < 4; ++nf) {
                const int c = colbase + nf * 16 + cl;
                sqj_[nf] = sq[c];
                yj_[nf]  = lbl[c];
            }
        }

        long af[4], bf[4];
#pragma unroll
        for (int mf = 0; mf < 4; ++mf)
            af[mf] = *(const long*)&As[cur][fragk + (wm * 64 + mf * 16 + cl) * 16];
#pragma unroll
        for (int nf = 0; nf < 4; ++nf)
            bf[nf] = *(const long*)&Bs[cur][fragk + (wn * 64 + nf * 16 + cl) * 16];

        __builtin_amdgcn_s_setprio(1);
#pragma unroll
        for (int mf = 0; mf < 4; ++mf)
#pragma unroll
            for (int nf = 0; nf < 4; ++nf)
                acc[mf][nf] = __builtin_amdgcn_mfma_f32_16x16x32_fp8_fp8(
                    af[mf], bf[nf], acc[mf][nf], 0, 0, 0);
        __builtin_amdgcn_s_setprio(0);
        // no trailing barrier: next iter's leading barrier provides the
        // consume-done guarantee for the ring buffer.
    }
#undef STAGE

    // ---- epilogue (r7/r10-verified) ----
    // C layout (m89, dtype-independent): col = lane&15, row = (lane>>4)*4 + reg
    const int rowbase = i0 + wm * 64;

    float cs_all[4], cs_same[4];      // col sums (over i) -> rows of panel bj
#pragma unroll
    for (int nf = 0; nf < 4; ++nf) { cs_all[nf] = 0.f; cs_same[nf] = 0.f; }

    // two batches of 8 rows each (mf in {2b, 2b+1}) to limit register peak
#pragma unroll
    for (int b = 0; b < 2; ++b) {
        float rs_all[8], rs_same[8];
#pragma unroll
        for (int e = 0; e < 8; ++e) { rs_all[e] = 0.f; rs_same[e] = 0.f; }

#pragma unroll
        for (int mh = 0; mh < 2; ++mh) {
            const int mf = 2 * b + mh;
#pragma unroll
            for (int r = 0; r < 4; ++r) {
                const int row   = rowbase + mf * 16 + g * 4 + r;
                const float sqi = sq[row];
                const int   yi  = lbl[row];
#pragma unroll
                for (int nf = 0; nf < 4; ++nf) {
                    float d2   = sqi + sqj_[nf] - 2.f * acc[mf][nf][r];
                    float dist = __builtin_amdgcn_sqrtf(fmaxf(d2, EPS_F));
                    if (diag) {
                        const int col = colbase + nf * 16 + cl;
                        if (row == col) dist = 1e-5f;   // exact diagonal sqrt(EPS)
                    }
                    const float dm = (yi == yj_[nf]) ? dist : 0.f;
                    cs_all[nf] += dist;
                    cs_same[nf] += dm;
                    rs_all[mh * 4 + r] += dist;
                    rs_same[mh * 4 + r] += dm;
                }
            }
        }

        // row direction (off-diag only): value-split 8 values over 16 lanes,
        // closing mask-1 stage completes the 16-lane sum; even-cl lanes own
        // entry e = cl>>1.
        if (!diag) {
#define RSTEP(h, mask, bit)                                                     \
            {                                                                   \
                const bool hi = (cl >> (bit)) & 1;                              \
                _Pragma("unroll")                                               \
                for (int j = 0; j < (h); ++j) {                                 \
                    float sa_ = hi ? rs_all[j] : rs_all[j + (h)];               \
                    float ka_ = hi ? rs_all[j + (h)] : rs_all[j];               \
                    rs_all[j] = ka_ + __shfl_xor(sa_, (mask));                  \
                    float ss_ = hi ? rs_same[j] : rs_same[j + (h)];             \
                    float ks_ = hi ? rs_same[j + (h)] : rs_same[j];             \
                    rs_same[j] = ks_ + __shfl_xor(ss_, (mask));                 \
                }                                                               \
            }
            RSTEP(4, 8, 3)
            RSTEP(2, 4, 2)
            RSTEP(1, 2, 1)
#undef RSTEP
            rs_all[0]  += __shfl_xor(rs_all[0], 1);   // closing stage (mask 1)
            rs_same[0] += __shfl_xor(rs_same[0], 1);

            const int e    = cl >> 1;
            const int rrow = rowbase + (2 * b + (e >> 2)) * 16 + g * 4 + (e & 3);
            if (!(cl & 1)) {
                atomicAdd(&sum_all[rrow],  rs_all[0]);
                atomicAdd(&sum_same[rrow], rs_same[0]);
            }
        }
    }

    // ---- col direction: value-split reduce 4 values over 4 g-lanes
    {
        const bool hi1 = (g >> 1) & 1;
#pragma unroll
        for (int j = 0; j < 2; ++j) {
            float sa_ = hi1 ? cs_all[j] : cs_all[j + 2];
            float ka_ = hi1 ? cs_all[j + 2] : cs_all[j];
            cs_all[j] = ka_ + __shfl_xor(sa_, 32);
            float ss_ = hi1 ? cs_same[j] : cs_same[j + 2];
            float ks_ = hi1 ? cs_same[j + 2] : cs_same[j];
            cs_same[j] = ks_ + __shfl_xor(ss_, 32);
        }
        const bool hi0 = g & 1;
        {
            float sa_ = hi0 ? cs_all[0] : cs_all[1];
            float ka_ = hi0 ? cs_all[1] : cs_all[0];
            cs_all[0] = ka_ + __shfl_xor(sa_, 16);
            float ss_ = hi0 ? cs_same[0] : cs_same[1];
            float ks_ = hi0 ? cs_same[1] : cs_same[0];
            cs_same[0] = ks_ + __shfl_xor(ss_, 16);
        }
        const int ccol = colbase + g * 16 + cl;
        atomicAdd(&sum_all[ccol],  cs_all[0]);
        atomicAdd(&sum_same[ccol], cs_same[0]);
    }
}

// ---------------------------------------------------------------------------
// Finalize: 32 blocks x 256 thr, one row per thread. Sums the 8 per-XCD
// partials; histogram from the 16 precomputed slices.
// ---------------------------------------------------------------------------
__global__ void finalize_kernel(const float* __restrict__ sum_same8,
                                const float* __restrict__ sum_all8,
                                const int* __restrict__ lbl,
                                const int* __restrict__ hist16,
                                float* __restrict__ out) {
    __shared__ int lh[64];
    __shared__ float wsums[4];
    const int tid = threadIdx.x;
    if (tid < 64) {
        int h = 0;
#pragma unroll
        for (int b = 0; b < 16; ++b) h += hist16[b * 64 + tid];
        lh[tid] = h;
    }
    __syncthreads();

    const int row = blockIdx.x * 256 + tid;
    float ss = 0.f, sa = 0.f;
#pragma unroll
    for (int x = 0; x < 8; ++x) {
        ss += sum_same8[(size_t)x * N + row];
        sa += sum_all8[(size_t)x * N + row];
    }

    const float cnt = (float)lh[lbl[row]];
    const float ap  = ss / cnt;
    const float an  = (sa - ss) / ((float)N - cnt);
    float local = fmaxf(ap - an + MARGIN, 0.f);

#pragma unroll
    for (int off = 32; off > 0; off >>= 1) local += __shfl_down(local, off);
    const int lane = tid & 63, wave = tid >> 6;
    if (lane == 0) wsums[wave] = local;
    __syncthreads();
    if (tid == 0)
        atomicAdd(out, (wsums[0] + wsums[1] + wsums[2] + wsums[3]) / (float)N);
}

// ---------------------------------------------------------------------------
extern "C" void kernel_launch(void* const* d_in, const int* in_sizes, int n_in,
                              void* d_out, int out_size, void* d_ws, size_t ws_size,
                              hipStream_t stream) {
    const float* xs     = (const float*)d_in[0];
    const int*   ys_raw = (const int*)d_in[1];

    float* ws          = (float*)d_ws;
    float* sum_same8   = ws;                         // [8][N]
    float* sum_all8    = ws + 8 * N;                 // [8][N]
    float* sqv         = ws + 16 * N;                // [N]
    int*   lbl         = (int*)(ws + 17 * N);        // [N]
    int*   hist16      = (int*)(ws + 18 * N);        // [16*64]
    unsigned char* x8  = (unsigned char*)(ws + 18 * N + 1024);  // [N*D] fp8 (2 MB)

    prep_kernel<<<N / 16, 256, 0, stream>>>(xs, ys_raw, x8, sqv, lbl, hist16,
                                            sum_same8, (float*)d_out);

    pair_kernel<<<NBLK, 256, 0, stream>>>(x8, lbl, sqv, sum_same8, sum_all8);

    finalize_kernel<<<32, 256, 0, stream>>>(sum_same8, sum_all8, lbl, hist16,
                                            (float*)d_out);
}